// Round 1
// baseline (3132.083 us; speedup 1.0000x reference)
//
#include <hip/hip_runtime.h>

#define N_TOKENS 131072
#define DIM 64
#define N_EMBED 1024
#define DECAYF 0.99f
#define OMDF 0.01f
#define EPSF 1e-5f

// Output layout (floats), reference return order:
// quantize_st [131072*64], diff [1], embed_ind [131072], new_embed [64*1024],
// new_cluster_size [1024], new_embed_avg [64*1024]
#define OFF_QST  ((size_t)0)
#define OFF_DIFF ((size_t)8388608)
#define OFF_IND  ((size_t)8388609)
#define OFF_NE   ((size_t)8519681)
#define OFF_NCS  ((size_t)8585217)
#define OFF_NEA  ((size_t)8586241)

// ws layout (floats):
// [0] diff_sum, [1] n_val, [2..1026) counts,
// [1026..66562) es[e*64+d], [66562..132098) embedT[e*64+d], [132098..133122) cnorm
#define WS_DIFF   0
#define WS_NVAL   1
#define WS_COUNTS 2
#define WS_ES     1026
#define WS_ET     66562
#define WS_CNORM  132098

__global__ __launch_bounds__(256) void vq_prep_transpose(
    const float* __restrict__ embed, float* __restrict__ embedT)
{
    int i = blockIdx.x * 256 + threadIdx.x;        // 65536 elems, coalesced read
    int d = i >> 10, e = i & 1023;
    embedT[e * DIM + d] = embed[i];
}

__global__ __launch_bounds__(256) void vq_prep_norm(
    const float* __restrict__ embedT, float* __restrict__ cnorm)
{
    int e = blockIdx.x * 256 + threadIdx.x;        // 1024
    const float4* c = (const float4*)(embedT + (size_t)e * DIM);
    float s = 0.f;
#pragma unroll
    for (int i = 0; i < 16; ++i) {
        float4 v = c[i];
        s = fmaf(v.x, v.x, s); s = fmaf(v.y, v.y, s);
        s = fmaf(v.z, v.z, s); s = fmaf(v.w, v.w, s);
    }
    cnorm[e] = s;
}

__global__ __launch_bounds__(256) void vq_main(
    const float* __restrict__ x, const float* __restrict__ embedT,
    const float* __restrict__ cnorm, float* __restrict__ out,
    float* __restrict__ counts, float* __restrict__ es,
    float* __restrict__ diff_sum)
{
    __shared__ float lcnt[N_EMBED];
    const int t = threadIdx.x;
    for (int i = t; i < N_EMBED; i += 256) lcnt[i] = 0.f;
    __syncthreads();

    const int n = blockIdx.x * 256 + t;            // one token per thread
    float4 xq[16];
    const float4* xv = (const float4*)(x + (size_t)n * DIM);
#pragma unroll
    for (int i = 0; i < 16; ++i) xq[i] = xv[i];

    float best = 3.4e38f;
    int bi = 0;
    for (int e = 0; e < N_EMBED; ++e) {
        const float4* ecol = (const float4*)(embedT + (size_t)e * DIM);
        float d0 = 0.f, d1 = 0.f, d2 = 0.f, d3 = 0.f;
#pragma unroll
        for (int i = 0; i < 16; ++i) {
            float4 ev = ecol[i];                   // wave-uniform address -> broadcast
            d0 = fmaf(xq[i].x, ev.x, d0);
            d1 = fmaf(xq[i].y, ev.y, d1);
            d2 = fmaf(xq[i].z, ev.z, d2);
            d3 = fmaf(xq[i].w, ev.w, d3);
        }
        float dot  = (d0 + d1) + (d2 + d3);
        float dist = fmaf(-2.f, dot, cnorm[e]);    // ||x||^2 const/row: argmin-invariant
        if (dist < best) { best = dist; bi = e; }  // strict < keeps first index (tie-break)
    }

    out[OFF_IND + n] = (float)bi;
    atomicAdd(&lcnt[bi], 1.f);

    // quantize (straight-through value), diff partial, embed_sum atomics
    const float4* qcol = (const float4*)(embedT + (size_t)bi * DIM);
    float4* qout = (float4*)(out + OFF_QST + (size_t)n * DIM);
    float ds = 0.f;
#pragma unroll
    for (int i = 0; i < 16; ++i) {
        float4 q = qcol[i];
        float4 xx = xq[i];
        float ex = q.x - xx.x, ey = q.y - xx.y, ez = q.z - xx.z, ew = q.w - xx.w;
        float4 st; st.x = xx.x + ex; st.y = xx.y + ey; st.z = xx.z + ez; st.w = xx.w + ew;
        qout[i] = st;
        ds = fmaf(ex, ex, ds); ds = fmaf(ey, ey, ds);
        ds = fmaf(ez, ez, ds); ds = fmaf(ew, ew, ds);
    }
    float* esc = es + (size_t)bi * DIM;
#pragma unroll
    for (int i = 0; i < 16; ++i) {
        atomicAdd(&esc[4 * i + 0], xq[i].x);
        atomicAdd(&esc[4 * i + 1], xq[i].y);
        atomicAdd(&esc[4 * i + 2], xq[i].z);
        atomicAdd(&esc[4 * i + 3], xq[i].w);
    }

    // diff: wave reduce then one atomic per wave
#pragma unroll
    for (int o = 32; o > 0; o >>= 1) ds += __shfl_down(ds, o, 64);
    if ((t & 63) == 0) atomicAdd(diff_sum, ds);

    // flush LDS histogram
    __syncthreads();
    for (int i = t; i < N_EMBED; i += 256) {
        float c = lcnt[i];
        if (c != 0.f) atomicAdd(&counts[i], c);
    }
}

__global__ __launch_bounds__(1024) void vq_final1(
    const float* __restrict__ cluster_size, const float* __restrict__ counts,
    const float* __restrict__ diff_sum, float* __restrict__ out,
    float* __restrict__ n_val)
{
    int e = threadIdx.x;                            // single block of 1024
    float ncs = cluster_size[e] * DECAYF + OMDF * counts[e];
    out[OFF_NCS + e] = ncs;
    __shared__ float red[16];
    float s = ncs;
#pragma unroll
    for (int o = 32; o > 0; o >>= 1) s += __shfl_down(s, o, 64);
    if ((e & 63) == 0) red[e >> 6] = s;
    __syncthreads();
    if (e == 0) {
        float nsum = 0.f;
#pragma unroll
        for (int i = 0; i < 16; ++i) nsum += red[i];
        *n_val = nsum;
        out[OFF_DIFF] = *diff_sum / (float)((size_t)N_TOKENS * DIM);
    }
}

__global__ __launch_bounds__(256) void vq_final2(
    const float* __restrict__ embed_avg, const float* __restrict__ es,
    const float* __restrict__ n_val, float* __restrict__ out)
{
    int i = blockIdx.x * 256 + threadIdx.x;         // 65536, [d][e] flat
    int e = i & 1023, d = i >> 10;
    float nea = embed_avg[i] * DECAYF + OMDF * es[(size_t)e * DIM + d];
    out[OFF_NEA + i] = nea;
    float ncs = out[OFF_NCS + e];
    float nsum = *n_val;
    float cs = (ncs + EPSF) / (nsum + (float)N_EMBED * EPSF) * nsum;
    out[OFF_NE + i] = nea / cs;
}

extern "C" void kernel_launch(void* const* d_in, const int* in_sizes, int n_in,
                              void* d_out, int out_size, void* d_ws, size_t ws_size,
                              hipStream_t stream)
{
    const float* x            = (const float*)d_in[0];
    const float* embed        = (const float*)d_in[1];
    const float* cluster_size = (const float*)d_in[2];
    const float* embed_avg    = (const float*)d_in[3];
    float* out = (float*)d_out;
    float* ws  = (float*)d_ws;

    float* diff_sum = ws + WS_DIFF;
    float* n_val    = ws + WS_NVAL;
    float* counts   = ws + WS_COUNTS;
    float* es       = ws + WS_ES;
    float* embedT   = ws + WS_ET;
    float* cnorm    = ws + WS_CNORM;

    // zero accumulators: diff_sum, n_val, counts, es
    hipMemsetAsync(d_ws, 0, (size_t)WS_ET * sizeof(float), stream);

    vq_prep_transpose<<<256, 256, 0, stream>>>(embed, embedT);
    vq_prep_norm<<<4, 256, 0, stream>>>(embedT, cnorm);
    vq_main<<<N_TOKENS / 256, 256, 0, stream>>>(x, embedT, cnorm, out, counts, es, diff_sum);
    vq_final1<<<1, 1024, 0, stream>>>(cluster_size, counts, diff_sum, out, n_val);
    vq_final2<<<256, 256, 0, stream>>>(embed_avg, es, n_val, out);
}